// Round 2
// baseline (610.393 us; speedup 1.0000x reference)
//
#include <hip/hip_runtime.h>

#define H 128
#define MAXLEN 431
#define BB 2048

// ws layout (floats): [0..127]=u2, [128..255]=u1, [256]=c, [384..2431]=hdot[b]

__global__ void prep_uv(const float* __restrict__ attn_w,
                        const float* __restrict__ attn_b,
                        const float* __restrict__ v,
                        float* __restrict__ ws) {
    int h = threadIdx.x;  // 128 threads
    float u1 = 0.f, u2 = 0.f;
    for (int e = 0; e < H; ++e) {
        float ve = v[e];
        u1 += ve * attn_w[e * 2 * H + h];        // w1[e,h]
        u2 += ve * attn_w[e * 2 * H + H + h];    // w2[e,h]
    }
    ws[h]     = u2;
    ws[H + h] = u1;
    if (h == 0) {
        float c = 0.f;
        for (int e = 0; e < H; ++e) c += attn_b[e] * v[e];
        ws[256] = c;
    }
}

__global__ void prep_hdot(const float* __restrict__ hidden,
                          float* __restrict__ ws) {
    int b = blockIdx.x * blockDim.x + threadIdx.x;  // 2048 total
    if (b >= BB) return;
    const float4* h4  = (const float4*)(hidden) + b * (H / 4);
    const float4* u14 = (const float4*)(ws + H);
    float a = 0.f;
    #pragma unroll
    for (int j = 0; j < H / 4; ++j) {
        float4 hv = h4[j];
        float4 uv = u14[j];
        a += hv.x * uv.x + hv.y * uv.y + hv.z * uv.z + hv.w * uv.w;
    }
    ws[384 + b] = a + ws[256];
}

__device__ __forceinline__ float dot4(float4 a, float4 b) {
    return a.x * b.x + a.y * b.y + a.z * b.z + a.w * b.w;
}

// Lane layout: lane = rk*8 + oct. Lane owns 16 consecutive floats (one 64B
// line) of row (group*16 + rk [+8 for B-half]), read as 4 back-to-back
// float4 loads. A wave covers 16 rows (8 KB) per iteration with 8 loads in
// flight. Per-row reduce = 3-step shfl_xor within the 8-lane oct group.
__global__ void main_scores(const float* __restrict__ k_emb,
                            const float* __restrict__ ws,
                            float* __restrict__ out) {
    const int lane = threadIdx.x & 63;
    const int oct  = lane & 7;   // position within row (which 64B line)
    const int rk   = lane >> 3;  // which of 8 rows in the half-group

    // u2 fragment for this lane: floats oct*16 .. oct*16+15
    const float4* u2p = (const float4*)ws + oct * 4;
    const float4 u0 = u2p[0], u1 = u2p[1], u2 = u2p[2], u3 = u2p[3];
    const float* hdot = ws + 384;

    const int wid = blockIdx.x * (blockDim.x >> 6) + (threadIdx.x >> 6);
    const int nw  = gridDim.x * (blockDim.x >> 6);
    const int NG  = MAXLEN * BB / 16;  // 55168 groups of 16 rows

    for (int g = wid; g < NG; g += nw) {
        // group g: rows g*16 .. g*16+15; row stride = 32 float4
        const float4* base = (const float4*)k_emb + (long long)g * 512 + rk * 32 + oct * 4;
        float4 a0 = base[0], a1 = base[1], a2 = base[2], a3 = base[3];
        const float4* baseB = base + 256;  // +8 rows
        float4 c0 = baseB[0], c1 = baseB[1], c2 = baseB[2], c3 = baseB[3];

        float pa = dot4(a0, u0) + dot4(a1, u1) + dot4(a2, u2) + dot4(a3, u3);
        float pb = dot4(c0, u0) + dot4(c1, u1) + dot4(c2, u2) + dot4(c3, u3);

        pa += __shfl_xor(pa, 1);  pb += __shfl_xor(pb, 1);
        pa += __shfl_xor(pa, 2);  pb += __shfl_xor(pb, 2);
        pa += __shfl_xor(pa, 4);  pb += __shfl_xor(pb, 4);

        if (oct == 0) {
            int rowA = g * 16 + rk;
            int rowB = rowA + 8;
            int lA = rowA >> 11, bA = rowA & (BB - 1);
            int lB = rowB >> 11, bB = rowB & (BB - 1);
            out[bA * MAXLEN + lA] = pa + hdot[bA];
            out[bB * MAXLEN + lB] = pb + hdot[bB];
        }
    }
}

extern "C" void kernel_launch(void* const* d_in, const int* in_sizes, int n_in,
                              void* d_out, int out_size, void* d_ws, size_t ws_size,
                              hipStream_t stream) {
    const float* hidden = (const float*)d_in[0];   // (1, 2048, 128)
    const float* k_emb  = (const float*)d_in[1];   // (431, 2048, 128)
    const float* attn_w = (const float*)d_in[2];   // (128, 256)
    const float* attn_b = (const float*)d_in[3];   // (128,)
    const float* v      = (const float*)d_in[4];   // (1, 128)
    float* out = (float*)d_out;                    // (2048, 431)
    float* ws  = (float*)d_ws;

    prep_uv<<<1, 128, 0, stream>>>(attn_w, attn_b, v, ws);
    prep_hdot<<<8, 256, 0, stream>>>(hidden, ws);
    // 1724 blocks * 4 waves = 6896 waves; 55168 / 6896 = exactly 8 groups/wave,
    // all waves co-resident (27 waves/CU) -> no tail.
    main_scores<<<1724, 256, 0, stream>>>(k_emb, ws, out);
}

// Round 3
// 602.760 us; speedup vs baseline: 1.0127x; 1.0127x over previous
//
#include <hip/hip_runtime.h>

#define H 128
#define MAXLEN 431
#define BB 2048

// ws layout (floats): [0..127]=u2, [384..2431]=hdot[b] (h.u1 + c folded in)

__device__ __forceinline__ float dot4(float4 a, float4 b) {
    return a.x * b.x + a.y * b.y + a.z * b.z + a.w * b.w;
}

// One fused prep kernel, 8 blocks x 256 threads.
// Each block redundantly computes u1 into LDS (waves 0-1) while waves 2-3
// compute u2 (block 0 stores it to ws). Then each block produces 256 hdots.
__global__ void prep(const float* __restrict__ attn_w,
                     const float* __restrict__ attn_b,
                     const float* __restrict__ v,
                     const float* __restrict__ hidden,
                     float* __restrict__ ws) {
    __shared__ float u1s[H];
    __shared__ float cs;
    const int t = threadIdx.x;

    if (t < 128) {                       // waves 0-1: u1 column t
        float acc = 0.f;
        for (int e = 0; e < H; ++e) acc += v[e] * attn_w[e * 2 * H + t];
        u1s[t] = acc;
    } else {                             // waves 2-3: u2 column t-128
        int h = t - 128;
        float acc = 0.f;
        for (int e = 0; e < H; ++e) acc += v[e] * attn_w[e * 2 * H + H + h];
        if (blockIdx.x == 0) ws[h] = acc;
    }
    if (t == 0) {
        float c = 0.f;
        for (int e = 0; e < H; ++e) c += attn_b[e] * v[e];
        cs = c;
    }
    __syncthreads();

    const int b = blockIdx.x * 256 + t;          // 8*256 = 2048
    const float4* h4  = (const float4*)hidden + b * (H / 4);
    const float4* u14 = (const float4*)u1s;
    float a = 0.f;
    #pragma unroll
    for (int j = 0; j < H / 4; ++j) a += dot4(h4[j], u14[j]);
    ws[384 + b] = a + cs;
}

// Lane layout: lane = rk*8 + oct. Lane owns one 64B line (16 floats) of row
// (16g + rk [+8]), read as 4 back-to-back float4 loads. Per iteration a wave
// covers a contiguous PAIR of 8KB groups (16 KB, 16 dwordx4 in flight).
// Per-row reduce = 3-step shfl_xor within the 8-lane oct group.
__global__ void main_scores(const float* __restrict__ k_emb,
                            const float* __restrict__ ws,
                            float* __restrict__ out) {
    const int lane = threadIdx.x & 63;
    const int oct  = lane & 7;
    const int rk   = lane >> 3;

    const float4* u2p = (const float4*)ws + oct * 4;
    const float4 u0 = u2p[0], u1 = u2p[1], u2 = u2p[2], u3 = u2p[3];
    const float* hdot = ws + 384;

    const int wid = blockIdx.x * (blockDim.x >> 6) + (threadIdx.x >> 6);
    const int nw  = gridDim.x * (blockDim.x >> 6);          // 6896
    const int NP  = MAXLEN * BB / 32;                       // 27584 pairs

    for (int p = wid; p < NP; p += nw) {                    // exactly 4 iters
        const int g0 = p * 2;
        // hoist L2-hot hdot loads so latency overlaps the HBM loads
        const int rowA0 = g0 * 16 + rk;
        const int bA0 = rowA0 & (BB - 1),        bB0 = (rowA0 + 8) & (BB - 1);
        const int bA1 = (rowA0 + 16) & (BB - 1), bB1 = (rowA0 + 24) & (BB - 1);
        float hA0 = hdot[bA0], hB0 = hdot[bB0];
        float hA1 = hdot[bA1], hB1 = hdot[bB1];

        const float4* base = (const float4*)k_emb + (long long)g0 * 512 + rk * 32 + oct * 4;
        float4 a0 = base[0],   a1 = base[1],   a2 = base[2],   a3 = base[3];
        float4 c0 = base[256], c1 = base[257], c2 = base[258], c3 = base[259];
        float4 d0 = base[512], d1 = base[513], d2 = base[514], d3 = base[515];
        float4 e0 = base[768], e1 = base[769], e2 = base[770], e3 = base[771];

        float pa = dot4(a0,u0) + dot4(a1,u1) + dot4(a2,u2) + dot4(a3,u3);
        float pb = dot4(c0,u0) + dot4(c1,u1) + dot4(c2,u2) + dot4(c3,u3);
        float pc = dot4(d0,u0) + dot4(d1,u1) + dot4(d2,u2) + dot4(d3,u3);
        float pd = dot4(e0,u0) + dot4(e1,u1) + dot4(e2,u2) + dot4(e3,u3);

        #pragma unroll
        for (int off = 1; off <= 4; off <<= 1) {
            pa += __shfl_xor(pa, off);
            pb += __shfl_xor(pb, off);
            pc += __shfl_xor(pc, off);
            pd += __shfl_xor(pd, off);
        }

        if (oct == 0) {
            const int lA0 = rowA0 >> 11;
            const int lB0 = (rowA0 + 8) >> 11;
            const int lA1 = (rowA0 + 16) >> 11;
            const int lB1 = (rowA0 + 24) >> 11;
            out[bA0 * MAXLEN + lA0] = pa + hA0;
            out[bB0 * MAXLEN + lB0] = pb + hB0;
            out[bA1 * MAXLEN + lA1] = pc + hA1;
            out[bB1 * MAXLEN + lB1] = pd + hB1;
        }
    }
}

extern "C" void kernel_launch(void* const* d_in, const int* in_sizes, int n_in,
                              void* d_out, int out_size, void* d_ws, size_t ws_size,
                              hipStream_t stream) {
    const float* hidden = (const float*)d_in[0];   // (1, 2048, 128)
    const float* k_emb  = (const float*)d_in[1];   // (431, 2048, 128)
    const float* attn_w = (const float*)d_in[2];   // (128, 256)
    const float* attn_b = (const float*)d_in[3];   // (128,)
    const float* v      = (const float*)d_in[4];   // (1, 128)
    float* out = (float*)d_out;                    // (2048, 431)
    float* ws  = (float*)d_ws;

    prep<<<8, 256, 0, stream>>>(attn_w, attn_b, v, hidden, ws);
    // 1724 blocks * 4 waves = 6896 waves; 27584 pairs / 6896 = exactly 4
    // iterations of 16 KB per wave, all waves co-resident, no tail.
    main_scores<<<1724, 256, 0, stream>>>(k_emb, ws, out);
}